// Round 9
// baseline (173.228 us; speedup 1.0000x reference)
//
#include <hip/hip_runtime.h>

// PerturbedTopK: B=128, N=1000, D=196, K=48, sigma=0.05
//
// Per (b,n) row: exact top-K of x[b,:] + sigma*noise[b,n,:], tie-break lowest
// index first (jax.lax.top_k), then scatter 1/N at (b, rank_by_index, d).
//
// R9 vs R8 (~57us invariant across 4 structurally different kernels; model:
// ~480cy/row issue vs ~1100cy/row wall -> 55% dependence-chain bubbles, TLP
// can't cover because every wave runs the same chain):
//  - TWO rows per wave, DPP reduction chains interleaved (wave_min2) so row
//    B's ops fill row A's stall slots; merged peel loop runs max(itA,itB)
//    ~2.8 iters instead of sum ~4.6.
//  - unified peel direction: w = v over selected (c>K, peel min out) or
//    w = -v over unselected (c<K, peel "max" in); selection update is XOR;
//    final-tie rule: down -> act ties with tp>=cv-need (drop highest d),
//    up -> act ties with tp<need (add lowest d).
//  - scatter + packed-u16 LDS accumulate + sparse flush unchanged (exact,
//    validated absmax=0.0 in R1/R3/R5/R6/R8).

#define BB 128
#define NN 1000
#define DD 196
#define KK 48

constexpr int SPLIT   = 16;           // blocks per b (n-range split)
constexpr int THREADS = 256;          // 4 waves
constexpr int NWAVES  = THREADS / 64;
constexpr int DH      = DD / 2;       // 98 packed columns
constexpr int LDSN    = KK * DH;      // 4704 u32

__device__ __forceinline__ int mbcnt64(unsigned long long m) {
  return __builtin_amdgcn_mbcnt_hi((unsigned)(m >> 32),
         __builtin_amdgcn_mbcnt_lo((unsigned)m, 0));
}

template <int CTRL>
__device__ __forceinline__ float dppmin(float v) {
  int t = __builtin_amdgcn_update_dpp(__float_as_int(v), __float_as_int(v),
                                      CTRL, 0xF, 0xF, false);
  return fminf(v, __int_as_float(t));
}

// two independent 64-lane min reductions, steps interleaved for ILP:
// row_shr:1/2/4/8 + row_bcast15/31, then readlane(63) broadcasts.
__device__ __forceinline__ void wave_min2(float a, float b,
                                          float& mmA, float& mmB) {
  a = dppmin<0x111>(a); b = dppmin<0x111>(b);
  a = dppmin<0x112>(a); b = dppmin<0x112>(b);
  a = dppmin<0x114>(a); b = dppmin<0x114>(b);
  a = dppmin<0x118>(a); b = dppmin<0x118>(b);
  a = dppmin<0x142>(a); b = dppmin<0x142>(b);
  a = dppmin<0x143>(a); b = dppmin<0x143>(b);
  mmA = __int_as_float(__builtin_amdgcn_readlane(__float_as_int(a), 63));
  mmB = __int_as_float(__builtin_amdgcn_readlane(__float_as_int(b), 63));
}

// one peel step for one row; mm/need/down wave-uniform, w/s per-lane.
__device__ __forceinline__ void resolve_row(
    float mm, bool down, int& need,
    float& w0, float& w1, float& w2, float& w3,
    bool& s0, bool& s1, bool& s2, bool& s3) {
  if (!need) return;
  const bool e0 = (w0 == mm), e1 = (w1 == mm), e2 = (w2 == mm), e3 = (w3 == mm);
  const unsigned long long E0 = __ballot(e0), E1 = __ballot(e1),
                           E2 = __ballot(e2), E3 = __ballot(e3);
  const int cv = __popcll(E0) + __popcll(E1) + __popcll(E2) + __popcll(E3);
  if (cv <= need) {
    s0 ^= e0; s1 ^= e1; s2 ^= e2; s3 ^= e3;   // e subset-of working set
    need -= cv;
    if (need) {
      const float PINF = __builtin_huge_valf();
      w0 = e0 ? PINF : w0; w1 = e1 ? PINF : w1;
      w2 = e2 ? PINF : w2; w3 = e3 ? PINF : w3;
    }
  } else {
    // final ties: d-order prefix (lane-major, slot-minor) = 4*lane+slot
    const int thr = down ? (cv - need) : need;
    int tp = mbcnt64(E0) + mbcnt64(E1) + mbcnt64(E2) + mbcnt64(E3);
    bool a0, a1, a2, a3;
    if (down) {  // drop the highest-d `need` ties
      a0 = e0 && tp >= thr; tp += e0; a1 = e1 && tp >= thr; tp += e1;
      a2 = e2 && tp >= thr; tp += e2; a3 = e3 && tp >= thr;
    } else {     // add the lowest-d `need` ties
      a0 = e0 && tp < thr;  tp += e0; a1 = e1 && tp < thr;  tp += e1;
      a2 = e2 && tp < thr;  tp += e2; a3 = e3 && tp < thr;
    }
    s0 ^= a0; s1 ^= a1; s2 ^= a2; s3 ^= a3;
    need = 0;
  }
}

__device__ __forceinline__ unsigned key_of(float v) {
  unsigned u = __float_as_uint(v);
  return u ^ (0x80000000u | (unsigned)((int)u >> 31));
}

// piv[b] = exact 48th-largest VALUE of x[b] (as float); one wave per b.
__global__ __launch_bounds__(64, 4) void pivot_kernel(
    const float* __restrict__ x, float* __restrict__ piv) {
  const int b    = blockIdx.x;
  const int lane = threadIdx.x;
  const bool lv  = lane < 49;
  float4 xv = make_float4(0.f, 0.f, 0.f, 0.f);
  if (lv) xv = *reinterpret_cast<const float4*>(x + b * DD + 4 * lane);
  unsigned xk0 = lv ? key_of(xv.x) : 0u;
  unsigned xk1 = lv ? key_of(xv.y) : 0u;
  unsigned xk2 = lv ? key_of(xv.z) : 0u;
  unsigned xk3 = lv ? key_of(xv.w) : 0u;
  unsigned p = 0u;
  #pragma unroll
  for (int bit = 31; bit >= 0; --bit) {
    unsigned cand = p | (1u << bit);
    int c = __popcll(__ballot(xk0 >= cand)) + __popcll(__ballot(xk1 >= cand))
          + __popcll(__ballot(xk2 >= cand)) + __popcll(__ballot(xk3 >= cand));
    if (c >= KK) p = cand;
  }
  if (lane == 0) {
    unsigned u = (p & 0x80000000u) ? (p ^ 0x80000000u) : ~p;
    piv[b] = __uint_as_float(u);
  }
}

__global__ __launch_bounds__(THREADS, 6) void ptopk_kernel(
    const float* __restrict__ x, const float* __restrict__ noise,
    const float* __restrict__ sigp, const float* __restrict__ pivp,
    float* __restrict__ out) {
  __shared__ unsigned cnt[LDSN];
  const int tid   = threadIdx.x;
  const int b     = blockIdx.x / SPLIT;
  const int split = blockIdx.x % SPLIT;
  const int n0    = (split * NN) / SPLIT;        // 62/63-row ranges
  const int n1    = ((split + 1) * NN) / SPLIT;

  for (int i = tid; i < LDSN; i += THREADS) cnt[i] = 0u;
  __syncthreads();

  const float sigma = sigp[0];
  const float piv   = pivp[b];
  const int lane = tid & 63;
  const int wv   = tid >> 6;
  const bool lv  = lane < 49;  // 49 lanes * 4 floats = 196 = D
  const float PINF = __builtin_huge_valf();
  const float NINF = -__builtin_huge_valf();

  float4 xv = make_float4(0.f, 0.f, 0.f, 0.f);
  if (lv) xv = *reinterpret_cast<const float4*>(x + b * DD + 4 * lane);

  const float* nbase = noise + (size_t)b * NN * DD;

  // wave wv owns row pairs {n0+2wv, n0+2wv+1} stride 2*NWAVES
  float4 nvA = make_float4(0.f, 0.f, 0.f, 0.f);
  float4 nvB = make_float4(0.f, 0.f, 0.f, 0.f);
  {
    const int rA0 = n0 + 2 * wv;
    if (lv && rA0 < n1)
      nvA = *reinterpret_cast<const float4*>(nbase + (size_t)rA0 * DD + 4 * lane);
    if (lv && rA0 + 1 < n1)
      nvB = *reinterpret_cast<const float4*>(nbase + (size_t)(rA0 + 1) * DD + 4 * lane);
  }

  for (int rA = n0 + 2 * wv; rA < n1; rA += 2 * NWAVES) {
    const float4 curA = nvA, curB = nvB;
    const bool hasB = (rA + 1) < n1;
    {
      const int rn = rA + 2 * NWAVES;
      if (lv && rn < n1)
        nvA = *reinterpret_cast<const float4*>(nbase + (size_t)rn * DD + 4 * lane);
      if (lv && rn + 1 < n1)
        nvB = *reinterpret_cast<const float4*>(nbase + (size_t)(rn + 1) * DD + 4 * lane);
    }

    // perturbed values; invalid lanes/rows -> -inf (never selected)
    const float vA0 = lv ? fmaf(sigma, curA.x, xv.x) : NINF;
    const float vA1 = lv ? fmaf(sigma, curA.y, xv.y) : NINF;
    const float vA2 = lv ? fmaf(sigma, curA.z, xv.z) : NINF;
    const float vA3 = lv ? fmaf(sigma, curA.w, xv.w) : NINF;
    const bool lvB = lv && hasB;
    const float vB0 = lvB ? fmaf(sigma, curB.x, xv.x) : NINF;
    const float vB1 = lvB ? fmaf(sigma, curB.y, xv.y) : NINF;
    const float vB2 = lvB ? fmaf(sigma, curB.z, xv.z) : NINF;
    const float vB3 = lvB ? fmaf(sigma, curB.w, xv.w) : NINF;

    bool sA0 = vA0 > piv, sA1 = vA1 > piv, sA2 = vA2 > piv, sA3 = vA3 > piv;
    bool sB0 = vB0 > piv, sB1 = vB1 > piv, sB2 = vB2 > piv, sB3 = vB3 > piv;
    const int cA = __popcll(__ballot(sA0)) + __popcll(__ballot(sA1))
                 + __popcll(__ballot(sA2)) + __popcll(__ballot(sA3));
    const int cB = __popcll(__ballot(sB0)) + __popcll(__ballot(sB1))
                 + __popcll(__ballot(sB2)) + __popcll(__ballot(sB3));

    const bool downA = cA >= KK, downB = cB >= KK;
    int needA = downA ? cA - KK : KK - cA;
    int needB = hasB ? (downB ? cB - KK : KK - cB) : 0;

    // unified working values: peel global min of w each step
    float wA0 = PINF, wA1 = PINF, wA2 = PINF, wA3 = PINF;
    float wB0 = PINF, wB1 = PINF, wB2 = PINF, wB3 = PINF;
    if (needA) {
      if (downA) { wA0 = sA0 ? vA0 : PINF; wA1 = sA1 ? vA1 : PINF;
                   wA2 = sA2 ? vA2 : PINF; wA3 = sA3 ? vA3 : PINF; }
      else       { wA0 = sA0 ? PINF : -vA0; wA1 = sA1 ? PINF : -vA1;
                   wA2 = sA2 ? PINF : -vA2; wA3 = sA3 ? PINF : -vA3; }
    }
    if (needB) {
      if (downB) { wB0 = sB0 ? vB0 : PINF; wB1 = sB1 ? vB1 : PINF;
                   wB2 = sB2 ? vB2 : PINF; wB3 = sB3 ? vB3 : PINF; }
      else       { wB0 = sB0 ? PINF : -vB0; wB1 = sB1 ? PINF : -vB1;
                   wB2 = sB2 ? PINF : -vB2; wB3 = sB3 ? PINF : -vB3; }
    }

    while (needA | needB) {
      float mmA, mmB;
      wave_min2(fminf(fminf(wA0, wA1), fminf(wA2, wA3)),
                fminf(fminf(wB0, wB1), fminf(wB2, wB3)), mmA, mmB);
      resolve_row(mmA, downA, needA, wA0, wA1, wA2, wA3, sA0, sA1, sA2, sA3);
      resolve_row(mmB, downB, needB, wB0, wB1, wB2, wB3, sB0, sB1, sB2, sB3);
    }

    // scatter A: rank-by-index k = prefix count of selected below d
    {
      const unsigned long long S0 = __ballot(sA0), S1 = __ballot(sA1),
                               S2 = __ballot(sA2), S3 = __ballot(sA3);
      int kp = mbcnt64(S0) + mbcnt64(S1) + mbcnt64(S2) + mbcnt64(S3);
      const int b2 = 2 * lane;
      if (sA0) atomicAdd(&cnt[kp * DH + b2],     1u);        kp += sA0 ? 1 : 0;
      if (sA1) atomicAdd(&cnt[kp * DH + b2],     0x10000u);  kp += sA1 ? 1 : 0;
      if (sA2) atomicAdd(&cnt[kp * DH + b2 + 1], 1u);        kp += sA2 ? 1 : 0;
      if (sA3) atomicAdd(&cnt[kp * DH + b2 + 1], 0x10000u);
    }
    // scatter B (all-false masks when !hasB -> no-ops)
    {
      const unsigned long long S0 = __ballot(sB0), S1 = __ballot(sB1),
                               S2 = __ballot(sB2), S3 = __ballot(sB3);
      int kp = mbcnt64(S0) + mbcnt64(S1) + mbcnt64(S2) + mbcnt64(S3);
      const int b2 = 2 * lane;
      if (sB0) atomicAdd(&cnt[kp * DH + b2],     1u);        kp += sB0 ? 1 : 0;
      if (sB1) atomicAdd(&cnt[kp * DH + b2],     0x10000u);  kp += sB1 ? 1 : 0;
      if (sB2) atomicAdd(&cnt[kp * DH + b2 + 1], 1u);        kp += sB2 ? 1 : 0;
      if (sB3) atomicAdd(&cnt[kp * DH + b2 + 1], 0x10000u);
    }
  }

  __syncthreads();

  // sparse flush: count * (1/N) into zero-initialized out
  const float invn = 1.0f / (float)NN;
  float* ob = out + (size_t)b * KK * DD;
  for (int i = tid; i < LDSN; i += THREADS) {
    const unsigned cv = cnt[i];
    if (cv) {
      const int k   = i / DH;
      const int dd2 = i - k * DH;
      const unsigned lo = cv & 0xFFFFu, hi = cv >> 16;
      float* p = ob + k * DD + 2 * dd2;
      if (lo) atomicAdd(p,     (float)lo * invn);
      if (hi) atomicAdd(p + 1, (float)hi * invn);
    }
  }
}

extern "C" void kernel_launch(void* const* d_in, const int* in_sizes, int n_in,
                              void* d_out, int out_size, void* d_ws, size_t ws_size,
                              hipStream_t stream) {
  (void)in_sizes; (void)n_in; (void)ws_size;
  const float* x     = (const float*)d_in[0];
  const float* noise = (const float*)d_in[1];
  const float* sig   = (const float*)d_in[2];
  float* out = (float*)d_out;
  float* piv = (float*)d_ws;

  (void)hipMemsetAsync(d_out, 0, (size_t)out_size * sizeof(float), stream);
  pivot_kernel<<<dim3(BB), dim3(64), 0, stream>>>(x, piv);
  ptopk_kernel<<<dim3(BB * SPLIT), dim3(THREADS), 0, stream>>>(x, noise, sig, piv, out);
}